// Round 1
// 380.541 us; speedup vs baseline: 1.2353x; 1.2353x over previous
//
#include <hip/hip_runtime.h>

#define NPTS   21
#define BATCH  16384
#define ROWS   (BATCH * NPTS)            // 344064 flat (b*21+n) rows
#define NGRP   ((BATCH + 2) / 3)         // 5462 groups of 3 batch elems (63 rows -> pad 64)
#define GPB    2                         // groups per block
#define NBLK   ((NGRP + GPB - 1) / GPB)  // 2731 blocks (exact: 5462 = 2731*2)
#define ZSTR   392                       // zb row stride in u16 (384+8 pad)
#define XTSTR  72                        // Xt row stride in u16 (144 B rows, 16B-aligned)

typedef unsigned short u16;
typedef unsigned int   u32;
typedef __bf16 bf16x8 __attribute__((ext_vector_type(8)));
typedef u16    u16x8  __attribute__((ext_vector_type(8)));
typedef float  f32x4  __attribute__((ext_vector_type(4)));

static __device__ __forceinline__ u16 f2bf(float f) {
  union { float f; u32 u; } v; v.f = f;
  u32 r = v.u + 0x7fffu + ((v.u >> 16) & 1u);   // RNE
  return (u16)(r >> 16);
}
static __device__ __forceinline__ float bf2f(u16 u) {
  union { u32 u; float f; } v; v.u = ((u32)u) << 16;
  return v.f;
}

// ---- prep: block-diag T1/T2 (bf16 hi+lo split) + transposed bf16 weights ---
__global__ void cheb_prep(const float* __restrict__ adj,
                          const float* __restrict__ weight,   // [3][1][128][128]
                          u16* __restrict__ TBG,              // [2][2][64][64]: (T1,T2) x (hi,lo), blockdiag
                          u16* __restrict__ WtG) {            // [128][384]: Wt[d][k*128+c]
  const int tid = threadIdx.x;
  const int gid = blockIdx.x * 256 + tid;
  for (int idx = gid; idx < 128 * 384; idx += 64 * 256) {
    int d  = idx / 384;
    int kc = idx - d * 384;                    // kc = k*128 + c
    WtG[idx] = f2bf(weight[kc * 128 + d]);     // weight[(k*128+c)*128 + d]
  }
  if (blockIdx.x == 0) {
    __shared__ float Ls[441];
    __shared__ float T2s[441];
    __shared__ float dsi[NPTS];
    if (tid < NPTS) {
      float s = 0.f;
      for (int m = 0; m < NPTS; ++m) s += adj[tid * NPTS + m];
      dsi[tid] = (s > 0.f) ? (1.0f / sqrtf(s)) : 0.f;
    }
    __syncthreads();
    for (int i = tid; i < 441; i += 256) {
      int n = i / NPTS, m = i - n * NPTS;
      Ls[i] = ((n == m) ? 1.f : 0.f) - dsi[n] * adj[i] * dsi[m];   // T1 = L
    }
    __syncthreads();
    for (int i = tid; i < 441; i += 256) {
      int n = i / NPTS, m = i - n * NPTS;
      float s = 0.f;
      for (int j = 0; j < NPTS; ++j) s += Ls[n * NPTS + j] * Ls[j * NPTS + m];
      T2s[i] = 2.f * s - ((n == m) ? 1.f : 0.f);                    // T2 = 2L^2 - I
    }
    __syncthreads();
    // block-diag 64x64 bf16 hi/lo pair per k (row/col 63 = pad = 0)
    for (int idx = tid; idx < 2 * 64 * 64; idx += 256) {
      int k = idx >> 12, rc = idx & 4095, r = rc >> 6, c = rc & 63;
      float v = 0.f;
      if (r < 63 && c < 63 && (r / 21) == (c / 21)) {
        int n = r % 21, m = c % 21;
        v = (k == 0) ? Ls[n * 21 + m] : T2s[n * 21 + m];
      }
      u16 hi = f2bf(v);
      TBG[(k * 2 + 0) * 4096 + rc] = hi;
      TBG[(k * 2 + 1) * 4096 + rc] = f2bf(v - bf2f(hi));
    }
  }
}

// ---- main: stage -> MFMA mix -> MFMA GEMM ----------------------------------
__global__ void __launch_bounds__(256, 2) cheb_main(
    const float* __restrict__ x,      // [16384][21][128] fp32
    const u16*  __restrict__ WtG,     // [128][384] bf16 bits
    const u16*  __restrict__ TBG,     // [2][2][64][64] bf16 bits
    const float* __restrict__ bias,   // [128]
    float* __restrict__ out) {        // [16384][21][128] fp32
  __shared__ __align__(16) u16 zb[64 * ZSTR];     // Z: 64 rows x 384 (k,c), bf16
  __shared__ __align__(16) u16 Xt[128 * XTSTR];   // X^T: Xt[c][m ^ key(c)], bf16

  const int tid  = threadIdx.x;
  const int wave = tid >> 6;
  const int lane = tid & 63;
  const int quad = lane >> 4;
  const int l15  = lane & 15;

  // persistent B fragments for the output GEMM: wave owns cols [wave*32, +31]
  u16x8 Breg[2][12];
  const int c0 = wave * 32 + l15;
  const int c1 = wave * 32 + 16 + l15;
#pragma unroll
  for (int t = 0; t < 2; ++t) {
    const u16* wp = WtG + (wave * 32 + t * 16 + l15) * 384 + quad * 8;
#pragma unroll
    for (int s = 0; s < 12; ++s) Breg[t][s] = *(const u16x8*)(wp + s * 32);
  }
  const float bias0 = bias[c0];
  const float bias1 = bias[c1];

  // persistent A fragments for the mix: waves 0,1 -> T1; waves 2,3 -> T2;
  // wave&1 picks the c-half. hi+lo split restores ~fp32 T precision.
  const int kk   = wave >> 1;
  const int half = wave & 1;
  u16x8 Thi[4][2], Tlo[4][2];                     // [mt][kt]
  {
    const u16* tb = TBG + kk * 2 * 4096;
#pragma unroll
    for (int mt = 0; mt < 4; ++mt)
#pragma unroll
      for (int kt = 0; kt < 2; ++kt) {
        const int off = (mt * 16 + l15) * 64 + kt * 32 + quad * 8;
        Thi[mt][kt] = *(const u16x8*)(tb + off);
        Tlo[mt][kt] = *(const u16x8*)(tb + 4096 + off);
      }
  }

  for (int it = 0; it < GPB; ++it) {
    const int grp = blockIdx.x * GPB + it;
    if (grp >= NGRP) break;                    // uniform across block
    const int gr0 = grp * 63;                  // first flat row of this group

    __syncthreads();                           // prev group's reads done
    // ---- stage x -> zb[:,0:128] (row-major) AND Xt (transposed, m-swizzled)
#pragma unroll
    for (int i = 0; i < 8; ++i) {
      int task = i * 256 + tid;                // 64 rows x 32 float4 chunks
      int r = task >> 5, q = task & 31;
      int gr = gr0 + r;
      float4 v = make_float4(0.f, 0.f, 0.f, 0.f);
      if (r < 63 && gr < ROWS) v = *(const float4*)(x + (size_t)gr * 128 + q * 4);
      u16 b0 = f2bf(v.x), b1 = f2bf(v.y), b2 = f2bf(v.z), b3 = f2bf(v.w);
      *(uint2*)(&zb[r * ZSTR + q * 4]) =
          make_uint2((u32)b0 | ((u32)b1 << 16), (u32)b2 | ((u32)b3 << 16));
      // transposed copy; XOR-swizzle on m spreads banks across lanes (q).
      // key is identical for c=4q..4q+3 since (c>>3) == (q>>1).
      const int cb4 = q * 4;
      const int rr  = r ^ (8 * ((q >> 1) & 7));
      Xt[(cb4 + 0) * XTSTR + rr] = b0;
      Xt[(cb4 + 1) * XTSTR + rr] = b1;
      Xt[(cb4 + 2) * XTSTR + rr] = b2;
      Xt[(cb4 + 3) * XTSTR + rr] = b3;
    }
    __syncthreads();

    // ---- mix via MFMA: Z_k = blockdiag(T_k) @ X, written to zb[:,(kk+1)*128..]
#pragma unroll
    for (int nt = 0; nt < 4; ++nt) {
      const int cb  = half * 64 + nt * 16;
      const int cc  = cb + l15;
      const int key = 8 * ((cc >> 3) & 7);     // same swizzle as the writes
      const u16* xp = Xt + cc * XTSTR;
      bf16x8 bx0 = __builtin_bit_cast(bf16x8, *(const u16x8*)(xp + ((quad * 8) ^ key)));
      bf16x8 bx1 = __builtin_bit_cast(bf16x8, *(const u16x8*)(xp + ((32 + quad * 8) ^ key)));
#pragma unroll
      for (int mt = 0; mt < 4; ++mt) {
        f32x4 z = {0.f, 0.f, 0.f, 0.f};
        z = __builtin_amdgcn_mfma_f32_16x16x32_bf16(
            __builtin_bit_cast(bf16x8, Thi[mt][0]), bx0, z, 0, 0, 0);
        z = __builtin_amdgcn_mfma_f32_16x16x32_bf16(
            __builtin_bit_cast(bf16x8, Tlo[mt][0]), bx0, z, 0, 0, 0);
        z = __builtin_amdgcn_mfma_f32_16x16x32_bf16(
            __builtin_bit_cast(bf16x8, Thi[mt][1]), bx1, z, 0, 0, 0);
        z = __builtin_amdgcn_mfma_f32_16x16x32_bf16(
            __builtin_bit_cast(bf16x8, Tlo[mt][1]), bx1, z, 0, 0, 0);
        const int rb = mt * 16 + quad * 4;     // D: row=quad*4+i, col=l15
#pragma unroll
        for (int i = 0; i < 4; ++i)
          zb[(rb + i) * ZSTR + (kk + 1) * 128 + cb + l15] = f2bf(z[i]);
      }
    }
    __syncthreads();

    // ---- GEMM: 64 rows x this wave's 32 cols, K = 384 (unchanged) ----
#pragma unroll
    for (int mt = 0; mt < 4; ++mt) {
      f32x4 acc0 = {0.f, 0.f, 0.f, 0.f};
      f32x4 acc1 = {0.f, 0.f, 0.f, 0.f};
      const u16* zrow = zb + (mt * 16 + l15) * ZSTR + quad * 8;
#pragma unroll
      for (int s = 0; s < 12; ++s) {
        bf16x8 a = __builtin_bit_cast(bf16x8, *(const u16x8*)(zrow + s * 32));
        acc0 = __builtin_amdgcn_mfma_f32_16x16x32_bf16(
            a, __builtin_bit_cast(bf16x8, Breg[0][s]), acc0, 0, 0, 0);
        acc1 = __builtin_amdgcn_mfma_f32_16x16x32_bf16(
            a, __builtin_bit_cast(bf16x8, Breg[1][s]), acc1, 0, 0, 0);
      }
      const int rbase = mt * 16 + quad * 4;    // D: row=quad*4+reg, col=l15
#pragma unroll
      for (int i = 0; i < 4; ++i) {
        int r = rbase + i;
        int gr = gr0 + r;
        if (r < 63 && gr < ROWS) {
          float* op = out + (size_t)gr * 128;
          op[c0] = acc0[i] + bias0;
          op[c1] = acc1[i] + bias1;
        }
      }
    }
  }
}

extern "C" void kernel_launch(void* const* d_in, const int* in_sizes, int n_in,
                              void* d_out, int out_size, void* d_ws, size_t ws_size,
                              hipStream_t stream) {
  (void)in_sizes; (void)n_in; (void)out_size; (void)ws_size;
  const float* x      = (const float*)d_in[0];
  const float* adj    = (const float*)d_in[1];
  const float* weight = (const float*)d_in[2];
  const float* bias   = (const float*)d_in[3];
  float* out = (float*)d_out;
  u16* TBG = (u16*)d_ws;                        // 32 KB: [2][2][64][64] bf16
  u16* WtG = (u16*)((char*)d_ws + 32768);       // 96 KB: [128][384] bf16
  cheb_prep<<<64, 256, 0, stream>>>(adj, weight, TBG, WtG);
  cheb_main<<<NBLK, 256, 0, stream>>>(x, WtG, TBG, bias, out);
}